// Round 17
// baseline (79.674 us; speedup 1.0000x reference)
//
#include <hip/hip_runtime.h>
#include <hip/hip_bf16.h>

#define Bv 8
#define Tv 64
#define Nv 128
#define P2v 256
#define KSv 64

typedef __attribute__((ext_vector_type(8))) short bf8;   // 8 bf16 in 4 VGPRs
typedef __attribute__((ext_vector_type(4))) float f4;    // MFMA C/D frag

#define MFMA16(a, b, c) __builtin_amdgcn_mfma_f32_16x16x32_bf16((a), (b), (c), 0, 0, 0)

__device__ __forceinline__ unsigned short f2bf(float f) {
  unsigned u = __float_as_uint(f);
  return (unsigned short)((u + 0x7fffu + ((u >> 16) & 1u)) >> 16);
}
__device__ __forceinline__ float bf2f(unsigned short h) {
  return __uint_as_float(((unsigned)h) << 16);
}
__device__ __forceinline__ unsigned pack2(unsigned short a, unsigned short b) {
  return (unsigned)a | ((unsigned)b << 16);
}
__device__ __forceinline__ ushort4 cvt_h(const float4& a) {
  ushort4 h;
  h.x = f2bf(a.x);
  h.y = f2bf(a.y);
  h.z = f2bf(a.z);
  h.w = f2bf(a.w);
  return h;
}

// [R][64] bf16, XOR-swizzled 16B granules. 128B row = one bank period ->
// measured conflict-free (qk Q/K reads, r13 av V^T reads).
__device__ __forceinline__ int swz64(int r, int c) {
  return r * 64 + ((((c >> 3)) ^ (r & 7)) << 3) + (c & 7);
}
// [R][32] bf16, XOR-swizzled 16B granules
__device__ __forceinline__ int swz32(int r, int c) {
  return r * 32 + ((((c >> 3)) ^ (r & 3)) << 3) + (c & 7);
}

// ---------------------------------------------------------------------------
// Prep: W_Q, W_K -> split hi/lo bf16 fragment-linear; W_V -> bf16 frag-linear.
// ---------------------------------------------------------------------------
__global__ __launch_bounds__(256) void prep_w_kernel(
    const float* __restrict__ Wq, const float* __restrict__ Wk,
    const float* __restrict__ Wv, unsigned short* __restrict__ wqh,
    unsigned short* __restrict__ wql, unsigned short* __restrict__ wkh,
    unsigned short* __restrict__ wkl, unsigned short* __restrict__ wvf) {
  const int e = blockIdx.x * 256 + threadIdx.x;  // 0..98303
  if (e < 32768) {
    const float* W = (e < 16384) ? Wq : Wk;
    unsigned short* oh = (e < 16384) ? wqh : wkh;
    unsigned short* ol = (e < 16384) ? wql : wkl;
    const int t = e & 16383;
    const int jj = t & 7, lane = (t >> 3) & 63, nt = (t >> 9) & 3, pt = t >> 11;
    const int p = pt * 32 + 8 * (lane >> 4) + jj;
    const int n = nt * 16 + (lane & 15);
    const float v = W[p * KSv + n];
    const unsigned short h = f2bf(v);
    oh[t] = h;
    ol[t] = f2bf(v - bf2f(h));
  } else {
    const int t = e - 32768;  // 0..65535
    const int jj = t & 7, lane = (t >> 3) & 63, nt = (t >> 9) & 15, pt = t >> 13;
    const int p = pt * 32 + 8 * (lane >> 4) + jj;
    const int q = nt * 16 + (lane & 15);
    wvf[t] = f2bf(Wv[p * P2v + q]);
  }
}

// ---------------------------------------------------------------------------
// Kernel A: per (b,t). Phase 1 (n-specialized): waves 0-3 Q, waves 4-7 K;
// X staged hi/lo in 32-col chunks through a DOUBLE-BUFFERED 2x8KB-hi/lo stage
// (aliasing the Q/K split region; total LDS exactly 64 KB) -> ONE barrier per
// chunk. Stage writes are single 16B packed stores. Phase 2 (row-spec):
// S = Q K^T / 8 (bf16x3), swapped-operand MFMA -> float4 S stores.
// (Byte-identical to round 16 — validated, best.)
// ---------------------------------------------------------------------------
__global__ __launch_bounds__(512) void qk_kernel(
    const float* __restrict__ x, const unsigned short* __restrict__ wqh,
    const unsigned short* __restrict__ wql,
    const unsigned short* __restrict__ wkh,
    const unsigned short* __restrict__ wkl, float* __restrict__ S) {
  __shared__ alignas(16) unsigned short sh[4 * Nv * KSv];  // 64 KB
  // stage dbuf d (d=0,1): hi at sh[d*8192 + swz32], lo at sh[d*8192 + 4096 + swz32]
  unsigned short* const qh_l = sh;          // phase-2 splits (alias stage)
  unsigned short* const ql_l = sh + 8192;
  unsigned short* const kh_l = sh + 16384;
  unsigned short* const kl_l = sh + 24576;
  const int bt = blockIdx.x;
  const float* __restrict__ X = x + (size_t)bt * (Nv * P2v);
  const int tid = threadIdx.x, lane = tid & 63, wid = tid >> 6;
  const int lg = lane >> 4, lr = lane & 15;
  const bool isQ = (wid < 4);
  const int nt = wid & 3;
  const unsigned short* __restrict__ wh = isQ ? wqh : wkh;
  const unsigned short* __restrict__ wl = isQ ? wql : wkl;

  const f4 zero = {0.f, 0.f, 0.f, 0.f};
  f4 acc[8];
#pragma unroll
  for (int rt = 0; rt < 8; ++rt) acc[rt] = zero;

  const int srow = tid >> 2;      // 0..127
  const int sp = (tid & 3) * 8;   // 0,8,16,24
  const float* __restrict__ Xrow = X + srow * P2v + sp;
  const int soff = swz32(srow, sp);  // 16B-aligned

  // Prologue: chunk 0 -> buf 0 (packed 16B stores); issue chunk-1 loads.
  float4 pv0 = *(const float4*)(Xrow);
  float4 pv1 = *(const float4*)(Xrow + 4);
  bf8 cwh = *(const bf8*)(wh + (nt * 64 + lane) * 8);
  bf8 cwl = *(const bf8*)(wl + (nt * 64 + lane) * 8);
  {
    ushort4 h0, l0, h1, l1;
    h0.x = f2bf(pv0.x); l0.x = f2bf(pv0.x - bf2f(h0.x));
    h0.y = f2bf(pv0.y); l0.y = f2bf(pv0.y - bf2f(h0.y));
    h0.z = f2bf(pv0.z); l0.z = f2bf(pv0.z - bf2f(h0.z));
    h0.w = f2bf(pv0.w); l0.w = f2bf(pv0.w - bf2f(h0.w));
    h1.x = f2bf(pv1.x); l1.x = f2bf(pv1.x - bf2f(h1.x));
    h1.y = f2bf(pv1.y); l1.y = f2bf(pv1.y - bf2f(h1.y));
    h1.z = f2bf(pv1.z); l1.z = f2bf(pv1.z - bf2f(h1.z));
    h1.w = f2bf(pv1.w); l1.w = f2bf(pv1.w - bf2f(h1.w));
    uint4 hp, lp;
    hp.x = pack2(h0.x, h0.y); hp.y = pack2(h0.z, h0.w);
    hp.z = pack2(h1.x, h1.y); hp.w = pack2(h1.z, h1.w);
    lp.x = pack2(l0.x, l0.y); lp.y = pack2(l0.z, l0.w);
    lp.z = pack2(l1.x, l1.y); lp.w = pack2(l1.z, l1.w);
    *(uint4*)(sh + soff) = hp;
    *(uint4*)(sh + 4096 + soff) = lp;
  }
  pv0 = *(const float4*)(Xrow + 32);
  pv1 = *(const float4*)(Xrow + 36);
  bf8 nwh = *(const bf8*)(wh + ((4 + nt) * 64 + lane) * 8);
  bf8 nwl = *(const bf8*)(wl + ((4 + nt) * 64 + lane) * 8);
  __syncthreads();

  for (int c = 0; c < 8; ++c) {
    const int rbase = (c & 1) * 8192;
#pragma unroll
    for (int rt = 0; rt < 8; ++rt) {
      const int xoff = rbase + swz32(rt * 16 + lr, lg * 8);
      const bf8 xh = *(const bf8*)(sh + xoff);
      const bf8 xl = *(const bf8*)(sh + 4096 + xoff);
      acc[rt] = MFMA16(xh, cwh, acc[rt]);
      acc[rt] = MFMA16(xh, cwl, acc[rt]);
      acc[rt] = MFMA16(xl, cwh, acc[rt]);
    }
    if (c < 7) {
      cwh = nwh;
      cwl = nwl;
      // convert chunk c+1 and write the OTHER buffer: its previous readers
      // (iteration c-1) finished before the end-of-iter-(c-1) barrier.
      ushort4 h0, l0, h1, l1;
      h0.x = f2bf(pv0.x); l0.x = f2bf(pv0.x - bf2f(h0.x));
      h0.y = f2bf(pv0.y); l0.y = f2bf(pv0.y - bf2f(h0.y));
      h0.z = f2bf(pv0.z); l0.z = f2bf(pv0.z - bf2f(h0.z));
      h0.w = f2bf(pv0.w); l0.w = f2bf(pv0.w - bf2f(h0.w));
      h1.x = f2bf(pv1.x); l1.x = f2bf(pv1.x - bf2f(h1.x));
      h1.y = f2bf(pv1.y); l1.y = f2bf(pv1.y - bf2f(h1.y));
      h1.z = f2bf(pv1.z); l1.z = f2bf(pv1.z - bf2f(h1.z));
      h1.w = f2bf(pv1.w); l1.w = f2bf(pv1.w - bf2f(h1.w));
      uint4 hp, lp;
      hp.x = pack2(h0.x, h0.y); hp.y = pack2(h0.z, h0.w);
      hp.z = pack2(h1.x, h1.y); hp.w = pack2(h1.z, h1.w);
      lp.x = pack2(l0.x, l0.y); lp.y = pack2(l0.z, l0.w);
      lp.z = pack2(l1.x, l1.y); lp.w = pack2(l1.z, l1.w);
      const int wbase = ((c + 1) & 1) * 8192;
      *(uint4*)(sh + wbase + soff) = hp;
      *(uint4*)(sh + wbase + 4096 + soff) = lp;
      if (c < 6) {  // issue chunk c+2 loads (drain across barrier + MFMA)
        pv0 = *(const float4*)(Xrow + (c + 2) * 32);
        pv1 = *(const float4*)(Xrow + (c + 2) * 32 + 4);
        const int wo = (((c + 2) * 4 + nt) * 64 + lane) * 8;
        nwh = *(const bf8*)(wh + wo);
        nwl = *(const bf8*)(wl + wo);
      }
      __syncthreads();  // single barrier per chunk
    }
  }
  __syncthreads();  // all stage reads done before split overwrite (alias)

  unsigned short* const oh = isQ ? qh_l : kh_l;
  unsigned short* const ol = isQ ? ql_l : kl_l;
#pragma unroll
  for (int rt = 0; rt < 8; ++rt) {
#pragma unroll
    for (int rr = 0; rr < 4; ++rr) {
      const int i = rt * 16 + 4 * lg + rr;
      const int ks = nt * 16 + lr;
      const int off = swz64(i, ks);
      const float v = acc[rt][rr];
      const unsigned short h = f2bf(v);
      oh[off] = h;
      ol[off] = f2bf(v - bf2f(h));
    }
  }
  __syncthreads();

  // Phase 2: S = Q K^T / 8 (bf16x3), SWAPPED operands:
  // D = K-frag * Q-frag => lane (lr,lg) holds S[r0+lr][n*16+4lg+rr] -> float4
  const int r0 = wid * 16;
  f4 aS[8];
#pragma unroll
  for (int n = 0; n < 8; ++n) aS[n] = zero;
#pragma unroll
  for (int kt2 = 0; kt2 < 2; ++kt2) {
    const int qoff = swz64(r0 + lr, kt2 * 32 + lg * 8);
    const bf8 fqh = *(const bf8*)(qh_l + qoff);
    const bf8 fql = *(const bf8*)(ql_l + qoff);
#pragma unroll
    for (int n = 0; n < 8; ++n) {
      const int koff = swz64(n * 16 + lr, kt2 * 32 + lg * 8);
      const bf8 fkh = *(const bf8*)(kh_l + koff);
      const bf8 fkl = *(const bf8*)(kl_l + koff);
      aS[n] = MFMA16(fkh, fqh, aS[n]);
      aS[n] = MFMA16(fkl, fqh, aS[n]);
      aS[n] = MFMA16(fkh, fql, aS[n]);
    }
  }
  float* __restrict__ Sb = S + (size_t)bt * (Nv * Nv);
#pragma unroll
  for (int n = 0; n < 8; ++n) {
    float4 v;
    v.x = aS[n][0] * 0.125f;
    v.y = aS[n][1] * 0.125f;
    v.z = aS[n][2] * 0.125f;
    v.w = aS[n][3] * 0.125f;
    *(float4*)(Sb + (r0 + lr) * Nv + n * 16 + 4 * lg) = v;
  }
}

// ---------------------------------------------------------------------------
// Kernel B: softmax over T axis; read fp32 S, write bf16 A.
// ---------------------------------------------------------------------------
__global__ __launch_bounds__(256) void softmax_t_kernel(
    const float* __restrict__ S, unsigned short* __restrict__ Abf) {
  const int idx = blockIdx.x * 256 + threadIdx.x;  // 0 .. B*N*N-1
  const int j = idx & (Nv - 1);
  const int i = (idx >> 7) & (Nv - 1);
  const int b = idx >> 14;
  const size_t base = ((size_t)b * Tv * Nv * Nv) + (size_t)i * Nv + j;

  float vals[Tv];
  float m = -1e30f;
#pragma unroll
  for (int t = 0; t < Tv; ++t) {
    const float v = S[base + (size_t)t * Nv * Nv];
    vals[t] = v;
    m = fmaxf(m, v);
  }
  float s = 0.f;
#pragma unroll
  for (int t = 0; t < Tv; ++t) {
    const float e = __expf(vals[t] - m);
    vals[t] = e;
    s += e;
  }
  const float inv = 1.f / s;
#pragma unroll
  for (int t = 0; t < Tv; ++t) {
    Abf[base + (size_t)t * Nv * Nv] = f2bf(vals[t] * inv);
  }
}

// ---------------------------------------------------------------------------
// Kernel C: per (b,t). Phase 1 (n-specialized, ntile = h*8 + wid): V = X@Wv
// with X-hi staged through a DOUBLE-BUFFERED 2x16KB stage -> one barrier per
// chunk (isolated retest of r12's av-dbuf WITHOUT the inline-A regression).
// A loaded directly from bf16 Abf. V^T via two [128][64] swz64 buffers
// (conflict-free, r13). Phase 2: out = A@V swapped -> float4 stores.
// LDS: 32 (stage dbuf) + 16 + 16 = 64 KB exactly.
// ---------------------------------------------------------------------------
__global__ __launch_bounds__(512) void av_kernel(
    const float* __restrict__ x, const unsigned short* __restrict__ wvf,
    const unsigned short* __restrict__ Abf, float* __restrict__ out) {
  __shared__ alignas(16) unsigned short xa[2 * Nv * KSv];  // 2 x 16 KB dbuf
  __shared__ alignas(16) unsigned short vthA[Nv * KSv];    // 16 KB V^T c0-63
  __shared__ alignas(16) unsigned short vthB[Nv * KSv];    // 16 KB V^T c64-127
  const int bt = blockIdx.x;
  const float* __restrict__ X = x + (size_t)bt * (Nv * P2v);
  const unsigned short* __restrict__ Ab = Abf + (size_t)bt * (Nv * Nv);
  float* __restrict__ ob = out + (size_t)bt * (Nv * P2v);
  const int tid = threadIdx.x, lane = tid & 63, wid = tid >> 6;
  const int lg = lane >> 4, lr = lane & 15;
  const int r0 = wid * 16;

  const f4 zero = {0.f, 0.f, 0.f, 0.f};
  f4 aV[16];  // [h*8 + rt] : ntile = h*8 + wid
#pragma unroll
  for (int n = 0; n < 16; ++n) aV[n] = zero;

  const int srow = tid >> 4;       // 0..31
  const int sp = (tid & 15) * 4;   // 0..60
  const float* __restrict__ Xrow = X + srow * P2v + sp;

  // Prologue: chunk 0 -> buf 0; issue chunk-1 loads; one barrier.
  float4 pf0 = *(const float4*)(Xrow);
  float4 pf1 = *(const float4*)(Xrow + 32 * P2v);
  float4 pf2 = *(const float4*)(Xrow + 64 * P2v);
  float4 pf3 = *(const float4*)(Xrow + 96 * P2v);
  {
    *(ushort4*)(xa + swz64(srow, sp)) = cvt_h(pf0);
    *(ushort4*)(xa + swz64(srow + 32, sp)) = cvt_h(pf1);
    *(ushort4*)(xa + swz64(srow + 64, sp)) = cvt_h(pf2);
    *(ushort4*)(xa + swz64(srow + 96, sp)) = cvt_h(pf3);
  }
  pf0 = *(const float4*)(Xrow + 64);
  pf1 = *(const float4*)(Xrow + 64 + 32 * P2v);
  pf2 = *(const float4*)(Xrow + 64 + 64 * P2v);
  pf3 = *(const float4*)(Xrow + 64 + 96 * P2v);
  __syncthreads();

  for (int c = 0; c < 4; ++c) {
    const int rbase = (c & 1) * 8192;
#pragma unroll
    for (int ktl = 0; ktl < 2; ++ktl) {
      const int kt = c * 2 + ktl;
#pragma unroll
      for (int h = 0; h < 2; ++h) {
        const int ntile = h * 8 + wid;
        const int o = ((kt * 16 + ntile) * 64 + lane) * 8;
        const bf8 fv = *(const bf8*)(wvf + o);
#pragma unroll
        for (int rt = 0; rt < 8; ++rt) {
          const bf8 xh = *(const bf8*)(
              xa + rbase + swz64(rt * 16 + lr, ktl * 32 + lg * 8));
          aV[h * 8 + rt] = MFMA16(xh, fv, aV[h * 8 + rt]);
        }
      }
    }
    if (c < 3) {
      // write chunk c+1 into the OTHER buffer (its iteration-(c-1) readers
      // finished before the end-of-iter-(c-1) barrier).
      const int wbase = ((c + 1) & 1) * 8192;
      *(ushort4*)(xa + wbase + swz64(srow, sp)) = cvt_h(pf0);
      *(ushort4*)(xa + wbase + swz64(srow + 32, sp)) = cvt_h(pf1);
      *(ushort4*)(xa + wbase + swz64(srow + 64, sp)) = cvt_h(pf2);
      *(ushort4*)(xa + wbase + swz64(srow + 96, sp)) = cvt_h(pf3);
      if (c < 2) {  // issue chunk c+2 loads (drain across barrier + MFMA)
        pf0 = *(const float4*)(Xrow + (c + 2) * 64);
        pf1 = *(const float4*)(Xrow + (c + 2) * 64 + 32 * P2v);
        pf2 = *(const float4*)(Xrow + (c + 2) * 64 + 64 * P2v);
        pf3 = *(const float4*)(Xrow + (c + 2) * 64 + 96 * P2v);
      }
      __syncthreads();  // single barrier per chunk
    }
  }

  // A fragments loaded AFTER phase 1 (caps VGPR through the chunk loop).
  bf8 af[4];
#pragma unroll
  for (int kt = 0; kt < 4; ++kt) {
    af[kt] = *(const bf8*)(Ab + (r0 + lr) * Nv + kt * 32 + lg * 8);
  }

  // Two halves: write V^T half (local rows 0..127) into the split swz64
  // buffers, sync, A@V (swapped), float4 out stores.
#pragma unroll
  for (int h = 0; h < 2; ++h) {
    if (h == 1) __syncthreads();  // half-0 reads done before overwrite
    const int ql = wid * 16 + lr;  // local row (wave's ntile = h*8+wid)
#pragma unroll
    for (int rt = 0; rt < 8; ++rt) {
      const int j0 = rt * 16 + 4 * lg;  // 0..124
      ushort4 pk;
      pk.x = f2bf(aV[h * 8 + rt][0]);
      pk.y = f2bf(aV[h * 8 + rt][1]);
      pk.z = f2bf(aV[h * 8 + rt][2]);
      pk.w = f2bf(aV[h * 8 + rt][3]);
      if (rt < 4) {
        *(ushort4*)(vthA + swz64(ql, j0)) = pk;
      } else {
        *(ushort4*)(vthB + swz64(ql, j0 - 64)) = pk;
      }
    }
    __syncthreads();

    // SWAPPED operands: D = V^T-frag * A-frag
    // => lane (lr,lg) holds out[r0+lr][h*128 + n*16 + 4lg + rr] -> float4
    f4 aO[8];
#pragma unroll
    for (int n = 0; n < 8; ++n) aO[n] = zero;
#pragma unroll
    for (int kt = 0; kt < 4; ++kt) {
#pragma unroll
      for (int n = 0; n < 8; ++n) {
        const unsigned short* vsrc = (kt < 2) ? vthA : vthB;
        const int col = (kt & 1) * 32 + lg * 8;
        const bf8 vf = *(const bf8*)(vsrc + swz64(n * 16 + lr, col));
        aO[n] = MFMA16(vf, af[kt], aO[n]);
      }
    }
#pragma unroll
    for (int n = 0; n < 8; ++n) {
      float4 v;
      v.x = aO[n][0];
      v.y = aO[n][1];
      v.z = aO[n][2];
      v.w = aO[n][3];
      *(float4*)(ob + (r0 + lr) * P2v + h * 128 + n * 16 + 4 * lg) = v;
    }
  }
}

extern "C" void kernel_launch(void* const* d_in, const int* in_sizes, int n_in,
                              void* d_out, int out_size, void* d_ws,
                              size_t ws_size, hipStream_t stream) {
  const float* x = (const float*)d_in[0];
  const float* Wq = (const float*)d_in[1];
  const float* Wk = (const float*)d_in[2];
  const float* Wv = (const float*)d_in[3];
  float* out = (float*)d_out;

  // ws: W frags (256 KB) | S fp32 (33.55 MB) | A bf16 (16.78 MB) = 50.6 MB
  unsigned short* wqh = (unsigned short*)d_ws;
  unsigned short* wql = wqh + 16384;
  unsigned short* wkh = wql + 16384;
  unsigned short* wkl = wkh + 16384;
  unsigned short* wvf = wkl + 16384;  // 65536 elems
  float* S = (float*)((char*)d_ws + 262144);
  unsigned short* Abf = (unsigned short*)((char*)d_ws + 262144 + 33554432);

  hipLaunchKernelGGL(prep_w_kernel, dim3(384), dim3(256), 0, stream, Wq, Wk,
                     Wv, wqh, wql, wkh, wkl, wvf);
  hipLaunchKernelGGL(qk_kernel, dim3(Bv * Tv), dim3(512), 0, stream, x, wqh,
                     wql, wkh, wkl, S);
  hipLaunchKernelGGL(softmax_t_kernel, dim3(Bv * Nv * Nv / 256), dim3(256), 0,
                     stream, S, Abf);
  hipLaunchKernelGGL(av_kernel, dim3(Bv * Tv), dim3(512), 0, stream, x, wvf,
                     Abf, out);
}

// Round 18
// 78.050 us; speedup vs baseline: 1.0208x; 1.0208x over previous
//
#include <hip/hip_runtime.h>
#include <hip/hip_bf16.h>

#define Bv 8
#define Tv 64
#define Nv 128
#define P2v 256
#define KSv 64

typedef __attribute__((ext_vector_type(8))) short bf8;   // 8 bf16 in 4 VGPRs
typedef __attribute__((ext_vector_type(4))) float f4;    // MFMA C/D frag

#define MFMA16(a, b, c) __builtin_amdgcn_mfma_f32_16x16x32_bf16((a), (b), (c), 0, 0, 0)

__device__ __forceinline__ unsigned short f2bf(float f) {
  unsigned u = __float_as_uint(f);
  return (unsigned short)((u + 0x7fffu + ((u >> 16) & 1u)) >> 16);
}
__device__ __forceinline__ float bf2f(unsigned short h) {
  return __uint_as_float(((unsigned)h) << 16);
}
__device__ __forceinline__ unsigned pack2(unsigned short a, unsigned short b) {
  return (unsigned)a | ((unsigned)b << 16);
}

// [R][64] bf16, XOR-swizzled 16B granules. 128B row = one bank period ->
// measured conflict-free (qk Q/K reads, r13 av V^T reads).
__device__ __forceinline__ int swz64(int r, int c) {
  return r * 64 + ((((c >> 3)) ^ (r & 7)) << 3) + (c & 7);
}
// [R][32] bf16, XOR-swizzled 16B granules
__device__ __forceinline__ int swz32(int r, int c) {
  return r * 32 + ((((c >> 3)) ^ (r & 3)) << 3) + (c & 7);
}

// ---------------------------------------------------------------------------
// Prep: W_Q, W_K -> split hi/lo bf16 fragment-linear; W_V -> bf16 frag-linear.
// ---------------------------------------------------------------------------
__global__ __launch_bounds__(256) void prep_w_kernel(
    const float* __restrict__ Wq, const float* __restrict__ Wk,
    const float* __restrict__ Wv, unsigned short* __restrict__ wqh,
    unsigned short* __restrict__ wql, unsigned short* __restrict__ wkh,
    unsigned short* __restrict__ wkl, unsigned short* __restrict__ wvf) {
  const int e = blockIdx.x * 256 + threadIdx.x;  // 0..98303
  if (e < 32768) {
    const float* W = (e < 16384) ? Wq : Wk;
    unsigned short* oh = (e < 16384) ? wqh : wkh;
    unsigned short* ol = (e < 16384) ? wql : wkl;
    const int t = e & 16383;
    const int jj = t & 7, lane = (t >> 3) & 63, nt = (t >> 9) & 3, pt = t >> 11;
    const int p = pt * 32 + 8 * (lane >> 4) + jj;
    const int n = nt * 16 + (lane & 15);
    const float v = W[p * KSv + n];
    const unsigned short h = f2bf(v);
    oh[t] = h;
    ol[t] = f2bf(v - bf2f(h));
  } else {
    const int t = e - 32768;  // 0..65535
    const int jj = t & 7, lane = (t >> 3) & 63, nt = (t >> 9) & 15, pt = t >> 13;
    const int p = pt * 32 + 8 * (lane >> 4) + jj;
    const int q = nt * 16 + (lane & 15);
    wvf[t] = f2bf(Wv[p * P2v + q]);
  }
}

// ---------------------------------------------------------------------------
// Kernel A: per (b,t). Phase 1 (n-specialized): waves 0-3 Q, waves 4-7 K;
// X staged hi/lo in 32-col chunks through a DOUBLE-BUFFERED 2x8KB-hi/lo stage
// (aliasing the Q/K split region; total LDS exactly 64 KB) -> ONE barrier per
// chunk. Stage writes are single 16B packed stores. Phase 2 (row-spec):
// S = Q K^T / 8 (bf16x3), swapped-operand MFMA -> float4 S stores.
// (Round-16 best — validated incl. post-timing replay.)
// ---------------------------------------------------------------------------
__global__ __launch_bounds__(512) void qk_kernel(
    const float* __restrict__ x, const unsigned short* __restrict__ wqh,
    const unsigned short* __restrict__ wql,
    const unsigned short* __restrict__ wkh,
    const unsigned short* __restrict__ wkl, float* __restrict__ S) {
  __shared__ alignas(16) unsigned short sh[4 * Nv * KSv];  // 64 KB
  // stage dbuf d (d=0,1): hi at sh[d*8192 + swz32], lo at sh[d*8192 + 4096 + swz32]
  unsigned short* const qh_l = sh;          // phase-2 splits (alias stage)
  unsigned short* const ql_l = sh + 8192;
  unsigned short* const kh_l = sh + 16384;
  unsigned short* const kl_l = sh + 24576;
  const int bt = blockIdx.x;
  const float* __restrict__ X = x + (size_t)bt * (Nv * P2v);
  const int tid = threadIdx.x, lane = tid & 63, wid = tid >> 6;
  const int lg = lane >> 4, lr = lane & 15;
  const bool isQ = (wid < 4);
  const int nt = wid & 3;
  const unsigned short* __restrict__ wh = isQ ? wqh : wkh;
  const unsigned short* __restrict__ wl = isQ ? wql : wkl;

  const f4 zero = {0.f, 0.f, 0.f, 0.f};
  f4 acc[8];
#pragma unroll
  for (int rt = 0; rt < 8; ++rt) acc[rt] = zero;

  const int srow = tid >> 2;      // 0..127
  const int sp = (tid & 3) * 8;   // 0,8,16,24
  const float* __restrict__ Xrow = X + srow * P2v + sp;
  const int soff = swz32(srow, sp);  // 16B-aligned

  // Prologue: chunk 0 -> buf 0 (packed 16B stores); issue chunk-1 loads.
  float4 pv0 = *(const float4*)(Xrow);
  float4 pv1 = *(const float4*)(Xrow + 4);
  bf8 cwh = *(const bf8*)(wh + (nt * 64 + lane) * 8);
  bf8 cwl = *(const bf8*)(wl + (nt * 64 + lane) * 8);
  {
    ushort4 h0, l0, h1, l1;
    h0.x = f2bf(pv0.x); l0.x = f2bf(pv0.x - bf2f(h0.x));
    h0.y = f2bf(pv0.y); l0.y = f2bf(pv0.y - bf2f(h0.y));
    h0.z = f2bf(pv0.z); l0.z = f2bf(pv0.z - bf2f(h0.z));
    h0.w = f2bf(pv0.w); l0.w = f2bf(pv0.w - bf2f(h0.w));
    h1.x = f2bf(pv1.x); l1.x = f2bf(pv1.x - bf2f(h1.x));
    h1.y = f2bf(pv1.y); l1.y = f2bf(pv1.y - bf2f(h1.y));
    h1.z = f2bf(pv1.z); l1.z = f2bf(pv1.z - bf2f(h1.z));
    h1.w = f2bf(pv1.w); l1.w = f2bf(pv1.w - bf2f(h1.w));
    uint4 hp, lp;
    hp.x = pack2(h0.x, h0.y); hp.y = pack2(h0.z, h0.w);
    hp.z = pack2(h1.x, h1.y); hp.w = pack2(h1.z, h1.w);
    lp.x = pack2(l0.x, l0.y); lp.y = pack2(l0.z, l0.w);
    lp.z = pack2(l1.x, l1.y); lp.w = pack2(l1.z, l1.w);
    *(uint4*)(sh + soff) = hp;
    *(uint4*)(sh + 4096 + soff) = lp;
  }
  pv0 = *(const float4*)(Xrow + 32);
  pv1 = *(const float4*)(Xrow + 36);
  bf8 nwh = *(const bf8*)(wh + ((4 + nt) * 64 + lane) * 8);
  bf8 nwl = *(const bf8*)(wl + ((4 + nt) * 64 + lane) * 8);
  __syncthreads();

  for (int c = 0; c < 8; ++c) {
    const int rbase = (c & 1) * 8192;
#pragma unroll
    for (int rt = 0; rt < 8; ++rt) {
      const int xoff = rbase + swz32(rt * 16 + lr, lg * 8);
      const bf8 xh = *(const bf8*)(sh + xoff);
      const bf8 xl = *(const bf8*)(sh + 4096 + xoff);
      acc[rt] = MFMA16(xh, cwh, acc[rt]);
      acc[rt] = MFMA16(xh, cwl, acc[rt]);
      acc[rt] = MFMA16(xl, cwh, acc[rt]);
    }
    if (c < 7) {
      cwh = nwh;
      cwl = nwl;
      // convert chunk c+1 and write the OTHER buffer: its previous readers
      // (iteration c-1) finished before the end-of-iter-(c-1) barrier.
      ushort4 h0, l0, h1, l1;
      h0.x = f2bf(pv0.x); l0.x = f2bf(pv0.x - bf2f(h0.x));
      h0.y = f2bf(pv0.y); l0.y = f2bf(pv0.y - bf2f(h0.y));
      h0.z = f2bf(pv0.z); l0.z = f2bf(pv0.z - bf2f(h0.z));
      h0.w = f2bf(pv0.w); l0.w = f2bf(pv0.w - bf2f(h0.w));
      h1.x = f2bf(pv1.x); l1.x = f2bf(pv1.x - bf2f(h1.x));
      h1.y = f2bf(pv1.y); l1.y = f2bf(pv1.y - bf2f(h1.y));
      h1.z = f2bf(pv1.z); l1.z = f2bf(pv1.z - bf2f(h1.z));
      h1.w = f2bf(pv1.w); l1.w = f2bf(pv1.w - bf2f(h1.w));
      uint4 hp, lp;
      hp.x = pack2(h0.x, h0.y); hp.y = pack2(h0.z, h0.w);
      hp.z = pack2(h1.x, h1.y); hp.w = pack2(h1.z, h1.w);
      lp.x = pack2(l0.x, l0.y); lp.y = pack2(l0.z, l0.w);
      lp.z = pack2(l1.x, l1.y); lp.w = pack2(l1.z, l1.w);
      const int wbase = ((c + 1) & 1) * 8192;
      *(uint4*)(sh + wbase + soff) = hp;
      *(uint4*)(sh + wbase + 4096 + soff) = lp;
      if (c < 6) {  // issue chunk c+2 loads (drain across barrier + MFMA)
        pv0 = *(const float4*)(Xrow + (c + 2) * 32);
        pv1 = *(const float4*)(Xrow + (c + 2) * 32 + 4);
        const int wo = (((c + 2) * 4 + nt) * 64 + lane) * 8;
        nwh = *(const bf8*)(wh + wo);
        nwl = *(const bf8*)(wl + wo);
      }
      __syncthreads();  // single barrier per chunk
    }
  }
  __syncthreads();  // all stage reads done before split overwrite (alias)

  unsigned short* const oh = isQ ? qh_l : kh_l;
  unsigned short* const ol = isQ ? ql_l : kl_l;
#pragma unroll
  for (int rt = 0; rt < 8; ++rt) {
#pragma unroll
    for (int rr = 0; rr < 4; ++rr) {
      const int i = rt * 16 + 4 * lg + rr;
      const int ks = nt * 16 + lr;
      const int off = swz64(i, ks);
      const float v = acc[rt][rr];
      const unsigned short h = f2bf(v);
      oh[off] = h;
      ol[off] = f2bf(v - bf2f(h));
    }
  }
  __syncthreads();

  // Phase 2: S = Q K^T / 8 (bf16x3), SWAPPED operands:
  // D = K-frag * Q-frag => lane (lr,lg) holds S[r0+lr][n*16+4lg+rr] -> float4
  const int r0 = wid * 16;
  f4 aS[8];
#pragma unroll
  for (int n = 0; n < 8; ++n) aS[n] = zero;
#pragma unroll
  for (int kt2 = 0; kt2 < 2; ++kt2) {
    const int qoff = swz64(r0 + lr, kt2 * 32 + lg * 8);
    const bf8 fqh = *(const bf8*)(qh_l + qoff);
    const bf8 fql = *(const bf8*)(ql_l + qoff);
#pragma unroll
    for (int n = 0; n < 8; ++n) {
      const int koff = swz64(n * 16 + lr, kt2 * 32 + lg * 8);
      const bf8 fkh = *(const bf8*)(kh_l + koff);
      const bf8 fkl = *(const bf8*)(kl_l + koff);
      aS[n] = MFMA16(fkh, fqh, aS[n]);
      aS[n] = MFMA16(fkl, fqh, aS[n]);
      aS[n] = MFMA16(fkh, fql, aS[n]);
    }
  }
  float* __restrict__ Sb = S + (size_t)bt * (Nv * Nv);
#pragma unroll
  for (int n = 0; n < 8; ++n) {
    float4 v;
    v.x = aS[n][0] * 0.125f;
    v.y = aS[n][1] * 0.125f;
    v.z = aS[n][2] * 0.125f;
    v.w = aS[n][3] * 0.125f;
    *(float4*)(Sb + (r0 + lr) * Nv + n * 16 + 4 * lg) = v;
  }
}

// ---------------------------------------------------------------------------
// Kernel B: softmax over T axis; read fp32 S, write bf16 A.
// ---------------------------------------------------------------------------
__global__ __launch_bounds__(256) void softmax_t_kernel(
    const float* __restrict__ S, unsigned short* __restrict__ Abf) {
  const int idx = blockIdx.x * 256 + threadIdx.x;  // 0 .. B*N*N-1
  const int j = idx & (Nv - 1);
  const int i = (idx >> 7) & (Nv - 1);
  const int b = idx >> 14;
  const size_t base = ((size_t)b * Tv * Nv * Nv) + (size_t)i * Nv + j;

  float vals[Tv];
  float m = -1e30f;
#pragma unroll
  for (int t = 0; t < Tv; ++t) {
    const float v = S[base + (size_t)t * Nv * Nv];
    vals[t] = v;
    m = fmaxf(m, v);
  }
  float s = 0.f;
#pragma unroll
  for (int t = 0; t < Tv; ++t) {
    const float e = __expf(vals[t] - m);
    vals[t] = e;
    s += e;
  }
  const float inv = 1.f / s;
#pragma unroll
  for (int t = 0; t < Tv; ++t) {
    Abf[base + (size_t)t * Nv * Nv] = f2bf(vals[t] * inv);
  }
}

// ---------------------------------------------------------------------------
// Kernel C: per (b,t). Phase 1 (n-specialized, ntile = h*8 + wid): V = X@Wv
// with X-hi staged in a dedicated 16 KB buffer, issue-early X prefetch.
// V^T consumed in two 128-col halves through TWO [128][64] swz64 buffers
// (conflict-free, r13). Phase 2: out = A(bf16) @ V, swapped -> float4 stores.
// (Round-16 best — single-buffer stage; av-dbuf retest (r17) regressed.)
// ---------------------------------------------------------------------------
__global__ __launch_bounds__(512) void av_kernel(
    const float* __restrict__ x, const unsigned short* __restrict__ wvf,
    const unsigned short* __restrict__ Abf, float* __restrict__ out) {
  __shared__ alignas(16) unsigned short xa[Nv * KSv];    // 16 KB X-hi stage
  __shared__ alignas(16) unsigned short vthA[Nv * KSv];  // 16 KB V^T c0-63
  __shared__ alignas(16) unsigned short vthB[Nv * KSv];  // 16 KB V^T c64-127
  const int bt = blockIdx.x;
  const float* __restrict__ X = x + (size_t)bt * (Nv * P2v);
  const unsigned short* __restrict__ Ab = Abf + (size_t)bt * (Nv * Nv);
  float* __restrict__ ob = out + (size_t)bt * (Nv * P2v);
  const int tid = threadIdx.x, lane = tid & 63, wid = tid >> 6;
  const int lg = lane >> 4, lr = lane & 15;
  const int r0 = wid * 16;

  const f4 zero = {0.f, 0.f, 0.f, 0.f};
  f4 aV[16];  // [h*8 + rt] : ntile = h*8 + wid
#pragma unroll
  for (int n = 0; n < 16; ++n) aV[n] = zero;

  const int srow = tid >> 4;       // 0..31
  const int sp = (tid & 15) * 4;   // 0..60
  const float* __restrict__ Xrow = X + srow * P2v + sp;

  // Prologue: prefetch chunk 0 (4 rows x float4 per thread)
  float4 pf0 = *(const float4*)(Xrow);
  float4 pf1 = *(const float4*)(Xrow + 32 * P2v);
  float4 pf2 = *(const float4*)(Xrow + 64 * P2v);
  float4 pf3 = *(const float4*)(Xrow + 96 * P2v);

  for (int c = 0; c < 4; ++c) {
    ushort4 q0, q1, q2, q3;
    q0.x = f2bf(pf0.x); q0.y = f2bf(pf0.y); q0.z = f2bf(pf0.z); q0.w = f2bf(pf0.w);
    q1.x = f2bf(pf1.x); q1.y = f2bf(pf1.y); q1.z = f2bf(pf1.z); q1.w = f2bf(pf1.w);
    q2.x = f2bf(pf2.x); q2.y = f2bf(pf2.y); q2.z = f2bf(pf2.z); q2.w = f2bf(pf2.w);
    q3.x = f2bf(pf3.x); q3.y = f2bf(pf3.y); q3.z = f2bf(pf3.z); q3.w = f2bf(pf3.w);

    __syncthreads();  // previous chunk's reads complete before overwrite
    *(ushort4*)(xa + swz64(srow, sp)) = q0;
    *(ushort4*)(xa + swz64(srow + 32, sp)) = q1;
    *(ushort4*)(xa + swz64(srow + 64, sp)) = q2;
    *(ushort4*)(xa + swz64(srow + 96, sp)) = q3;

    if (c < 3) {  // issue-early next chunk
      pf0 = *(const float4*)(Xrow + (c + 1) * 64);
      pf1 = *(const float4*)(Xrow + (c + 1) * 64 + 32 * P2v);
      pf2 = *(const float4*)(Xrow + (c + 1) * 64 + 64 * P2v);
      pf3 = *(const float4*)(Xrow + (c + 1) * 64 + 96 * P2v);
    }
    __syncthreads();
#pragma unroll
    for (int ktl = 0; ktl < 2; ++ktl) {
      const int kt = c * 2 + ktl;
#pragma unroll
      for (int h = 0; h < 2; ++h) {
        const int ntile = h * 8 + wid;
        const int o = ((kt * 16 + ntile) * 64 + lane) * 8;
        const bf8 fv = *(const bf8*)(wvf + o);
#pragma unroll
        for (int rt = 0; rt < 8; ++rt) {
          const bf8 xh =
              *(const bf8*)(xa + swz64(rt * 16 + lr, ktl * 32 + lg * 8));
          aV[h * 8 + rt] = MFMA16(xh, fv, aV[h * 8 + rt]);
        }
      }
    }
  }

  // A fragments loaded AFTER phase 1 (caps VGPR through the chunk loop).
  bf8 af[4];
#pragma unroll
  for (int kt = 0; kt < 4; ++kt) {
    af[kt] = *(const bf8*)(Ab + (r0 + lr) * Nv + kt * 32 + lg * 8);
  }

  // Two halves: write V^T half (local rows 0..127) into the split swz64
  // buffers, sync, A@V (swapped), float4 out stores.
#pragma unroll
  for (int h = 0; h < 2; ++h) {
    if (h == 1) __syncthreads();  // half-0 reads done before overwrite
    const int ql = wid * 16 + lr;  // local row (wave's ntile = h*8+wid)
#pragma unroll
    for (int rt = 0; rt < 8; ++rt) {
      const int j0 = rt * 16 + 4 * lg;  // 0..124
      ushort4 pk;
      pk.x = f2bf(aV[h * 8 + rt][0]);
      pk.y = f2bf(aV[h * 8 + rt][1]);
      pk.z = f2bf(aV[h * 8 + rt][2]);
      pk.w = f2bf(aV[h * 8 + rt][3]);
      if (rt < 4) {
        *(ushort4*)(vthA + swz64(ql, j0)) = pk;
      } else {
        *(ushort4*)(vthB + swz64(ql, j0 - 64)) = pk;
      }
    }
    __syncthreads();

    // SWAPPED operands: D = V^T-frag * A-frag
    // => lane (lr,lg) holds out[r0+lr][h*128 + n*16 + 4lg + rr] -> float4
    f4 aO[8];
#pragma unroll
    for (int n = 0; n < 8; ++n) aO[n] = zero;
#pragma unroll
    for (int kt = 0; kt < 4; ++kt) {
#pragma unroll
      for (int n = 0; n < 8; ++n) {
        const unsigned short* vsrc = (kt < 2) ? vthA : vthB;
        const int col = (kt & 1) * 32 + lg * 8;
        const bf8 vf = *(const bf8*)(vsrc + swz64(n * 16 + lr, col));
        aO[n] = MFMA16(vf, af[kt], aO[n]);
      }
    }
#pragma unroll
    for (int n = 0; n < 8; ++n) {
      float4 v;
      v.x = aO[n][0];
      v.y = aO[n][1];
      v.z = aO[n][2];
      v.w = aO[n][3];
      *(float4*)(ob + (r0 + lr) * P2v + h * 128 + n * 16 + 4 * lg) = v;
    }
  }
}

extern "C" void kernel_launch(void* const* d_in, const int* in_sizes, int n_in,
                              void* d_out, int out_size, void* d_ws,
                              size_t ws_size, hipStream_t stream) {
  const float* x = (const float*)d_in[0];
  const float* Wq = (const float*)d_in[1];
  const float* Wk = (const float*)d_in[2];
  const float* Wv = (const float*)d_in[3];
  float* out = (float*)d_out;

  // ws: W frags (256 KB) | S fp32 (33.55 MB) | A bf16 (16.78 MB) = 50.6 MB
  unsigned short* wqh = (unsigned short*)d_ws;
  unsigned short* wql = wqh + 16384;
  unsigned short* wkh = wql + 16384;
  unsigned short* wkl = wkh + 16384;
  unsigned short* wvf = wkl + 16384;  // 65536 elems
  float* S = (float*)((char*)d_ws + 262144);
  unsigned short* Abf = (unsigned short*)((char*)d_ws + 262144 + 33554432);

  hipLaunchKernelGGL(prep_w_kernel, dim3(384), dim3(256), 0, stream, Wq, Wk,
                     Wv, wqh, wql, wkh, wkl, wvf);
  hipLaunchKernelGGL(qk_kernel, dim3(Bv * Tv), dim3(512), 0, stream, x, wqh,
                     wql, wkh, wkl, S);
  hipLaunchKernelGGL(softmax_t_kernel, dim3(Bv * Nv * Nv / 256), dim3(256), 0,
                     stream, S, Abf);
  hipLaunchKernelGGL(av_kernel, dim3(Bv * Tv), dim3(512), 0, stream, x, wvf,
                     Abf, out);
}